// Round 1
// baseline (91.029 us; speedup 1.0000x reference)
//
#include <hip/hip_runtime.h>
#include <math.h>

#define DM 128
#define SEQ 512
#define NTOK 2048
#define NH 8
#define HD 16
#define NE 256

__device__ __forceinline__ float sigmoid_f(float v) { return 1.0f / (1.0f + expf(-v)); }

// reduce 4 per-token sums across a 128-thread (2-wave) block
__device__ __forceinline__ void block_reduce4(float vals[4], float (*red)[4], int tid) {
#pragma unroll
  for (int off = 32; off; off >>= 1) {
#pragma unroll
    for (int g = 0; g < 4; ++g) vals[g] += __shfl_down(vals[g], off, 64);
  }
  const int lane = tid & 63, w = tid >> 6;
  if (lane == 0) {
#pragma unroll
    for (int g = 0; g < 4; ++g) red[w][g] = vals[g];
  }
  __syncthreads();
#pragma unroll
  for (int g = 0; g < 4; ++g) vals[g] = red[0][g] + red[1][g];
  __syncthreads();
}

// ---------------- Kernel A: rmsnorm + QKV + RoPE + elu+1 ----------------
__global__ __launch_bounds__(128) void k_qkv(
    const float* __restrict__ x, const float* __restrict__ g1,
    const float* __restrict__ wq, const float* __restrict__ bq,
    const float* __restrict__ wk, const float* __restrict__ bk,
    const float* __restrict__ wv, const float* __restrict__ bv,
    float* __restrict__ q, float* __restrict__ k, float* __restrict__ v) {
  const int tid = threadIdx.x;
  const int n0 = blockIdx.x * 4;
  __shared__ float h1[4][DM];
  __shared__ float red[2][4];
  __shared__ float qr[4][DM];
  __shared__ float kr[4][DM];

  float xv[4], ss[4];
#pragma unroll
  for (int g = 0; g < 4; ++g) {
    xv[g] = x[(n0 + g) * DM + tid];
    ss[g] = xv[g] * xv[g];
  }
  block_reduce4(ss, red, tid);
  const float gv = g1[tid];
#pragma unroll
  for (int g = 0; g < 4; ++g) {
    float rinv = 1.0f / sqrtf(ss[g] * (1.0f / 128.0f) + 1e-6f);
    h1[g][tid] = gv * xv[g] * rinv;
  }
  __syncthreads();

  float aq[4] = {0, 0, 0, 0}, ak[4] = {0, 0, 0, 0}, av[4] = {0, 0, 0, 0};
  for (int d = 0; d < DM; ++d) {
    float wqv = wq[d * DM + tid];
    float wkv = wk[d * DM + tid];
    float wvv = wv[d * DM + tid];
#pragma unroll
    for (int g = 0; g < 4; ++g) {
      float hv = h1[g][d];
      aq[g] = fmaf(hv, wqv, aq[g]);
      ak[g] = fmaf(hv, wkv, ak[g]);
      av[g] = fmaf(hv, wvv, av[g]);
    }
  }
  const float bqv = bq[tid], bkv = bk[tid], bvv = bv[tid];
#pragma unroll
  for (int g = 0; g < 4; ++g) {
    qr[g][tid] = aq[g] + bqv;
    kr[g][tid] = ak[g] + bkv;
    v[(n0 + g) * DM + tid] = av[g] + bvv;
  }
  __syncthreads();

  // RoPE (NeoX half-split within each 16-dim head) + elu+1
  const int i = tid & 15;
  const int j = i & 7;
  const int hi = i & 8;
  const int lo_idx = tid & ~8;  // position of x1 within this head
  const float invf = expf(-(float)j * 1.1512925464970229f);  // ln(10000)/8
#pragma unroll
  for (int g = 0; g < 4; ++g) {
    int t = (n0 + g) & (SEQ - 1);
    float ang = (float)t * invf;
    float s = sinf(ang), c = cosf(ang);
    float x1q = qr[g][lo_idx], x2q = qr[g][lo_idx + 8];
    float x1k = kr[g][lo_idx], x2k = kr[g][lo_idx + 8];
    float rq = hi ? (x1q * s + x2q * c) : (x1q * c - x2q * s);
    float rk = hi ? (x1k * s + x2k * c) : (x1k * c - x2k * s);
    rq = (rq > 0.0f) ? rq + 1.0f : expf(rq);  // elu(x)+1
    rk = (rk > 0.0f) ? rk + 1.0f : expf(rk);
    q[(n0 + g) * DM + tid] = rq;
    k[(n0 + g) * DM + tid] = rk;
  }
}

// ---------------- Kernel B: ctx = k^T v  and k_sum, per (b,h) ----------------
__global__ __launch_bounds__(1024) void k_ctx(
    const float* __restrict__ k, const float* __restrict__ v,
    float* __restrict__ ctx, float* __restrict__ ksum) {
  const int bh = blockIdx.x;  // 0..31
  const int b = bh >> 3, h = bh & 7;
  const int tid = threadIdx.x;
  const int qt = tid >> 8, p = tid & 255, d = p >> 4, e = p & 15;
  const float* kb = k + (size_t)b * SEQ * DM + h * HD;
  const float* vb = v + (size_t)b * SEQ * DM + h * HD;
  float acc = 0.0f, ks = 0.0f;
  for (int tt = 0; tt < SEQ / 4; ++tt) {
    int t = qt * (SEQ / 4) + tt;
    float kv = kb[t * DM + d];
    float vv = vb[t * DM + e];
    acc = fmaf(kv, vv, acc);
    ks += kv;
  }
  __shared__ float lds[4][256];
  lds[qt][p] = acc;
  __syncthreads();
  if (qt == 0) ctx[bh * 256 + p] = lds[0][p] + lds[1][p] + lds[2][p] + lds[3][p];
  __syncthreads();
  lds[qt][p] = ks;
  __syncthreads();
  if (qt == 0 && e == 0)
    ksum[bh * HD + d] = lds[0][p] + lds[1][p] + lds[2][p] + lds[3][p];
}

// ------- Kernel C: attn out + wo + turbo_quant + swiglu + residual + rmsnorm -------
__global__ __launch_bounds__(128) void k_attn(
    const float* __restrict__ x, const float* __restrict__ q,
    const float* __restrict__ ctx, const float* __restrict__ ksum,
    const float* __restrict__ wo, const float* __restrict__ bo,
    const float* __restrict__ rot, const float* __restrict__ tqs,
    const float* __restrict__ w1, const float* __restrict__ b1,
    const float* __restrict__ w2, const float* __restrict__ b2,
    const float* __restrict__ g2,
    float* __restrict__ xmid, float* __restrict__ h2o) {
  const int tid = threadIdx.x;
  const int n0 = blockIdx.x * 4;
  const int b = n0 >> 9;
  __shared__ float ctxs[NH * 256];  // 8KB
  __shared__ float kss[DM];
  __shared__ float row[4][DM];
  __shared__ float red[2][4];

#pragma unroll
  for (int r = 0; r < 16; ++r) ctxs[r * DM + tid] = ctx[b * 2048 + r * DM + tid];
  kss[tid] = ksum[b * DM + tid];
#pragma unroll
  for (int g = 0; g < 4; ++g) row[g][tid] = q[(n0 + g) * DM + tid];
  __syncthreads();

  const int h = tid >> 4, e = tid & 15;
  float att[4];
#pragma unroll
  for (int g = 0; g < 4; ++g) {
    float o = 0.0f, qk = 0.0f;
#pragma unroll
    for (int d = 0; d < HD; ++d) {
      float qv = row[g][h * HD + d];
      o = fmaf(qv, ctxs[h * 256 + d * 16 + e], o);
      qk = fmaf(qv, kss[h * HD + d], qk);
    }
    att[g] = o / (qk + 1e-6f);
  }
  __syncthreads();
#pragma unroll
  for (int g = 0; g < 4; ++g) row[g][tid] = att[g];
  __syncthreads();

  // @ wo + bo
  float acc[4] = {0, 0, 0, 0};
  for (int d = 0; d < DM; ++d) {
    float w = wo[d * DM + tid];
#pragma unroll
    for (int g = 0; g < 4; ++g) acc[g] = fmaf(row[g][d], w, acc[g]);
  }
  const float bov = bo[tid];
  __syncthreads();
#pragma unroll
  for (int g = 0; g < 4; ++g) row[g][tid] = acc[g] + bov;
  __syncthreads();

  // turbo_quant: y = attn_out @ rot
  float y[4] = {0, 0, 0, 0};
  for (int d = 0; d < DM; ++d) {
    float r = rot[d * DM + tid];
#pragma unroll
    for (int g = 0; g < 4; ++g) y[g] = fmaf(row[g][d], r, y[g]);
  }
  float ssq[4];
#pragma unroll
  for (int g = 0; g < 4; ++g) ssq[g] = y[g] * y[g];
  block_reduce4(ssq, red, tid);
  const float tqsv = tqs[tid];
  float tqv[4];
#pragma unroll
  for (int g = 0; g < 4; ++g) {
    float mag = sqrtf(ssq[g] * (1.0f / 128.0f) + 1e-6f);
    float phase = y[g] / mag;
    tqv[g] = rintf(phase * 8.0f) * 0.125f * mag * tqsv;  // STE fwd = quant*mag*scale
  }
  __syncthreads();
#pragma unroll
  for (int g = 0; g < 4; ++g) row[g][tid] = tqv[g];
  __syncthreads();

  // swiglu
  float a1[4] = {0, 0, 0, 0}, a2[4] = {0, 0, 0, 0};
  for (int d = 0; d < DM; ++d) {
    float w1v = w1[d * DM + tid];
    float w2v = w2[d * DM + tid];
#pragma unroll
    for (int g = 0; g < 4; ++g) {
      float t = row[g][d];
      a1[g] = fmaf(t, w1v, a1[g]);
      a2[g] = fmaf(t, w2v, a2[g]);
    }
  }
  const float b1v = b1[tid], b2v = b2[tid];
  float xm[4];
#pragma unroll
  for (int g = 0; g < 4; ++g) {
    float gate = a1[g] + b1v;
    float up = a2[g] + b2v;
    float swv = gate * sigmoid_f(gate) * up;
    xm[g] = x[(n0 + g) * DM + tid] + swv;
    xmid[(n0 + g) * DM + tid] = xm[g];
    ssq[g] = xm[g] * xm[g];
  }
  block_reduce4(ssq, red, tid);
  const float g2v = g2[tid];
#pragma unroll
  for (int g = 0; g < 4; ++g) {
    float rinv = 1.0f / sqrtf(ssq[g] * (1.0f / 128.0f) + 1e-6f);
    h2o[(n0 + g) * DM + tid] = g2v * xm[g] * rinv;
  }
}

// ---------------- Kernel D: MoE (gate softmax top-2, experts, swiglu, consensus) ----------------
__global__ __launch_bounds__(256) void k_moe(
    const float* __restrict__ h2, const float* __restrict__ xmid,
    const float* __restrict__ gate_w, const float* __restrict__ gate_b,
    const float* __restrict__ exp_w,
    const float* __restrict__ mw1, const float* __restrict__ mb1,
    const float* __restrict__ mw2, const float* __restrict__ mb2,
    float* __restrict__ out_x, float* __restrict__ out_cons) {
  const int tid = threadIdx.x;
  const int n0 = blockIdx.x * 4;
  __shared__ float h2s[4][DM];
  __shared__ float rv[4][NE];
  __shared__ int ri[4][NE];
  __shared__ float smax[4], ssum[4], sl1[4];
  __shared__ int si0[4], si1[4];
  __shared__ float el[4][2][DM];
  __shared__ float was[4][DM];
  __shared__ float vr[256][2];

  for (int idx = tid; idx < 4 * DM; idx += 256)
    h2s[idx >> 7][idx & 127] = h2[(size_t)n0 * DM + idx];
  __syncthreads();

  // gate logits (each thread owns one of 256 experts)
  float lg[4] = {0, 0, 0, 0};
  for (int d = 0; d < DM; ++d) {
    float gw = gate_w[d * NE + tid];
#pragma unroll
    for (int g = 0; g < 4; ++g) lg[g] = fmaf(h2s[g][d], gw, lg[g]);
  }
  const float gbv = gate_b[tid];
#pragma unroll
  for (int g = 0; g < 4; ++g) lg[g] += gbv;

  // tree 1: max + argmax (tie -> lower index, matches top_k)
#pragma unroll
  for (int g = 0; g < 4; ++g) { rv[g][tid] = lg[g]; ri[g][tid] = tid; }
  __syncthreads();
  for (int s = 128; s > 0; s >>= 1) {
    if (tid < s) {
#pragma unroll
      for (int g = 0; g < 4; ++g) {
        float va = rv[g][tid], vb = rv[g][tid + s];
        int ia = ri[g][tid], ib = ri[g][tid + s];
        if (vb > va || (vb == va && ib < ia)) { rv[g][tid] = vb; ri[g][tid] = ib; }
      }
    }
    __syncthreads();
  }
  if (tid == 0) {
#pragma unroll
    for (int g = 0; g < 4; ++g) { smax[g] = rv[g][0]; si0[g] = ri[g][0]; }
  }
  __syncthreads();

  // tree 2: sum of exp
#pragma unroll
  for (int g = 0; g < 4; ++g) rv[g][tid] = expf(lg[g] - smax[g]);
  __syncthreads();
  for (int s = 128; s > 0; s >>= 1) {
    if (tid < s) {
#pragma unroll
      for (int g = 0; g < 4; ++g) rv[g][tid] += rv[g][tid + s];
    }
    __syncthreads();
  }
  if (tid == 0) {
#pragma unroll
    for (int g = 0; g < 4; ++g) ssum[g] = rv[g][0];
  }
  __syncthreads();

  // tree 3: second max
#pragma unroll
  for (int g = 0; g < 4; ++g) {
    rv[g][tid] = (tid == si0[g]) ? -INFINITY : lg[g];
    ri[g][tid] = tid;
  }
  __syncthreads();
  for (int s = 128; s > 0; s >>= 1) {
    if (tid < s) {
#pragma unroll
      for (int g = 0; g < 4; ++g) {
        float va = rv[g][tid], vb = rv[g][tid + s];
        int ia = ri[g][tid], ib = ri[g][tid + s];
        if (vb > va || (vb == va && ib < ia)) { rv[g][tid] = vb; ri[g][tid] = ib; }
      }
    }
    __syncthreads();
  }
  if (tid == 0) {
#pragma unroll
    for (int g = 0; g < 4; ++g) { sl1[g] = rv[g][0]; si1[g] = ri[g][0]; }
  }
  __syncthreads();

  // top-2 weights (computed redundantly per thread)
  float w0[4], w1c[4];
#pragma unroll
  for (int g = 0; g < 4; ++g) {
    float v0 = 1.0f / ssum[g];                       // exp(max-max)/Z
    float v1 = expf(sl1[g] - smax[g]) / ssum[g];
    float wsum = v0 + v1 + 1e-6f;
    w0[g] = v0 / wsum;
    w1c[g] = v1 / wsum;
  }

  // gathered expert matmuls: half the block does expert0, half expert1
  const int which = tid >> 7, o = tid & 127;
  size_t base[4];
#pragma unroll
  for (int g = 0; g < 4; ++g)
    base[g] = (size_t)(which ? si1[g] : si0[g]) * (DM * DM);
  float ea[4] = {0, 0, 0, 0};
  for (int d = 0; d < DM; ++d) {
#pragma unroll
    for (int g = 0; g < 4; ++g)
      ea[g] = fmaf(h2s[g][d], exp_w[base[g] + d * DM + o], ea[g]);
  }
#pragma unroll
  for (int g = 0; g < 4; ++g) el[g][which][o] = ea[g];
  __syncthreads();
  if (which == 0) {
#pragma unroll
    for (int g = 0; g < 4; ++g)
      was[g][o] = w0[g] * el[g][0][o] + w1c[g] * el[g][1][o];
  }
  __syncthreads();

  // moe swiglu: half-block gg handles tokens 2*gg, 2*gg+1
  const int gg = which;
  float a1[2] = {0, 0}, a2[2] = {0, 0};
  for (int d = 0; d < DM; ++d) {
    float w1v = mw1[d * DM + o];
    float w2v = mw2[d * DM + o];
#pragma unroll
    for (int jj = 0; jj < 2; ++jj) {
      float t = was[2 * gg + jj][d];
      a1[jj] = fmaf(t, w1v, a1[jj]);
      a2[jj] = fmaf(t, w2v, a2[jj]);
    }
  }
  const float mb1v = mb1[o], mb2v = mb2[o];
#pragma unroll
  for (int jj = 0; jj < 2; ++jj) {
    int g = 2 * gg + jj;
    float gate = a1[jj] + mb1v;
    float up = a2[jj] + mb2v;
    float swv = gate * sigmoid_f(gate) * up;
    out_x[(size_t)(n0 + g) * DM + o] = xmid[(size_t)(n0 + g) * DM + o] + swv;
    float d0 = el[g][0][o] - swv;
    float d1 = el[g][1][o] - swv;
    vr[tid][jj] = w0[g] * d0 * d0 + w1c[g] * d1 * d1;
  }
  __syncthreads();
  for (int s = 64; s > 0; s >>= 1) {
    if (o < s) {
#pragma unroll
      for (int jj = 0; jj < 2; ++jj) vr[tid][jj] += vr[tid + s][jj];
    }
    __syncthreads();
  }
  if (o == 0) {
#pragma unroll
    for (int jj = 0; jj < 2; ++jj)
      out_cons[n0 + 2 * gg + jj] = expf(-vr[tid][jj] * (1.0f / 128.0f));
  }
}

extern "C" void kernel_launch(void* const* d_in, const int* in_sizes, int n_in,
                              void* d_out, int out_size, void* d_ws, size_t ws_size,
                              hipStream_t stream) {
  const float* x = (const float*)d_in[0];
  const float* g1 = (const float*)d_in[1];
  const float* wq = (const float*)d_in[2];
  const float* bq = (const float*)d_in[3];
  const float* wk = (const float*)d_in[4];
  const float* bk = (const float*)d_in[5];
  const float* wv = (const float*)d_in[6];
  const float* bv = (const float*)d_in[7];
  const float* wo = (const float*)d_in[8];
  const float* bo = (const float*)d_in[9];
  const float* rot = (const float*)d_in[10];
  const float* tqs = (const float*)d_in[11];
  const float* sw1 = (const float*)d_in[12];
  const float* sb1 = (const float*)d_in[13];
  const float* sw2 = (const float*)d_in[14];
  const float* sb2 = (const float*)d_in[15];
  const float* g2 = (const float*)d_in[16];
  const float* gw = (const float*)d_in[17];
  const float* gb = (const float*)d_in[18];
  const float* ew = (const float*)d_in[19];
  const float* mw1 = (const float*)d_in[20];
  const float* mb1 = (const float*)d_in[21];
  const float* mw2 = (const float*)d_in[22];
  const float* mb2 = (const float*)d_in[23];

  float* ws = (float*)d_ws;
  float* q = ws;                     // 262144
  float* k = ws + 262144;            // 262144
  float* v = ws + 524288;            // 262144
  float* ctx = ws + 786432;          // 8192
  float* ksum = ws + 794624;         // 512
  float* xmid = ws + 795136;         // 262144
  float* h2 = ws + 1057280;          // 262144
  float* out_x = (float*)d_out;
  float* out_c = out_x + (size_t)NTOK * DM;

  hipLaunchKernelGGL(k_qkv, dim3(NTOK / 4), dim3(128), 0, stream,
                     x, g1, wq, bq, wk, bk, wv, bv, q, k, v);
  hipLaunchKernelGGL(k_ctx, dim3(32), dim3(1024), 0, stream, k, v, ctx, ksum);
  hipLaunchKernelGGL(k_attn, dim3(NTOK / 4), dim3(128), 0, stream,
                     x, q, ctx, ksum, wo, bo, rot, tqs, sw1, sb1, sw2, sb2, g2,
                     xmid, h2);
  hipLaunchKernelGGL(k_moe, dim3(NTOK / 4), dim3(256), 0, stream,
                     h2, xmid, gw, gb, ew, mw1, mb1, mw2, mb2, out_x, out_c);
}

// Round 4
// 67.213 us; speedup vs baseline: 1.3543x; 1.3543x over previous
//
#include <hip/hip_runtime.h>
#include <math.h>

#define DM 128
#define SEQ 512
#define NTOK 2048
#define NH 8
#define HD 16
#define NE 256

__device__ __forceinline__ float sigmoid_f(float v) { return 1.0f / (1.0f + expf(-v)); }

__device__ __forceinline__ float wave_sum64(float v) {
#pragma unroll
  for (int m = 32; m; m >>= 1) v += __shfl_xor(v, m, 64);
  return v;
}

// ---------------- Kernel A: rmsnorm + QKV + RoPE + elu+1 ----------------
// 512 threads: o = tid&127 (output), ks = tid>>7 (k-slice / token)
__global__ __launch_bounds__(512) void k_qkv(
    const float* __restrict__ x, const float* __restrict__ g1,
    const float* __restrict__ wq, const float* __restrict__ bq,
    const float* __restrict__ wk, const float* __restrict__ bk,
    const float* __restrict__ wv, const float* __restrict__ bv_,
    float* __restrict__ q, float* __restrict__ k, float* __restrict__ v) {
  const int tid = threadIdx.x;
  const int o = tid & 127, ks = tid >> 7;
  const int n0 = blockIdx.x * 4;
  __shared__ float h1[4][DM];
  __shared__ float qr[4][DM], kr[4][DM];
  __shared__ float red3[4][4][DM][3];  // [slice][token][o][q/k/v] 24KB
  __shared__ float wredA[8];

  // rmsnorm: token ks handled by its 128-thread group (2 waves)
  float xv = x[(n0 + ks) * DM + o];
  float s = wave_sum64(xv * xv);
  if ((tid & 63) == 0) wredA[tid >> 6] = s;
  __syncthreads();
  float tot = wredA[2 * ks] + wredA[2 * ks + 1];
  float rinv = 1.0f / sqrtf(tot * (1.0f / 128.0f) + 1e-6f);
  h1[ks][o] = g1[o] * xv * rinv;
  __syncthreads();

  // QKV partial matmul over d-slice [32*ks, 32*ks+32)
  float aq[4] = {0, 0, 0, 0}, ak[4] = {0, 0, 0, 0}, av[4] = {0, 0, 0, 0};
  const int d0 = ks * 32;
  for (int dd = 0; dd < 32; ++dd) {
    int d = d0 + dd;
    float wqv = wq[d * DM + o], wkv = wk[d * DM + o], wvv = wv[d * DM + o];
#pragma unroll
    for (int g = 0; g < 4; ++g) {
      float hv = h1[g][d];
      aq[g] = fmaf(hv, wqv, aq[g]);
      ak[g] = fmaf(hv, wkv, ak[g]);
      av[g] = fmaf(hv, wvv, av[g]);
    }
  }
#pragma unroll
  for (int g = 0; g < 4; ++g) {
    red3[ks][g][o][0] = aq[g];
    red3[ks][g][o][1] = ak[g];
    red3[ks][g][o][2] = av[g];
  }
  __syncthreads();
  // finalize token ks, output o
  float sq = bq[o], sk = bk[o], sv = bv_[o];
#pragma unroll
  for (int s2 = 0; s2 < 4; ++s2) {
    sq += red3[s2][ks][o][0];
    sk += red3[s2][ks][o][1];
    sv += red3[s2][ks][o][2];
  }
  qr[ks][o] = sq;
  kr[ks][o] = sk;
  v[(n0 + ks) * DM + o] = sv;
  __syncthreads();

  // RoPE (NeoX half-split within each 16-dim head) + elu+1
  const int i = o & 15, j = i & 7, hi = i & 8, lo = o & ~8;
  const float invf = expf(-(float)j * 1.1512925464970229f);  // ln(10000)/8
  int t = (n0 + ks) & (SEQ - 1);
  float ang = (float)t * invf;
  float sn = sinf(ang), cs = cosf(ang);
  float x1q = qr[ks][lo], x2q = qr[ks][lo + 8];
  float x1k = kr[ks][lo], x2k = kr[ks][lo + 8];
  float rq = hi ? (x1q * sn + x2q * cs) : (x1q * cs - x2q * sn);
  float rk = hi ? (x1k * sn + x2k * cs) : (x1k * cs - x2k * sn);
  rq = (rq > 0.0f) ? rq + 1.0f : expf(rq);
  rk = (rk > 0.0f) ? rk + 1.0f : expf(rk);
  q[(n0 + ks) * DM + o] = rq;
  k[(n0 + ks) * DM + o] = rk;
}

// ---------------- Kernel B: ctx/ksum partials, per (b,h,tchunk) ----------------
// grid 256 = 8 tchunks x 32 bh; 256 threads (d,e)
__global__ __launch_bounds__(256) void k_ctxp(
    const float* __restrict__ k, const float* __restrict__ v,
    float* __restrict__ ctxp, float* __restrict__ ksump) {
  const int bh = blockIdx.x & 31, tc = blockIdx.x >> 5;
  const int b = bh >> 3, h = bh & 7;
  const int p = threadIdx.x, d = p >> 4, e = p & 15;
  const float* kb = k + (size_t)b * SEQ * DM + h * HD;
  const float* vb = v + (size_t)b * SEQ * DM + h * HD;
  float acc = 0.0f, kss = 0.0f;
  for (int tt = 0; tt < 64; ++tt) {
    int t = tc * 64 + tt;
    float kv = kb[t * DM + d];
    float vv = vb[t * DM + e];
    acc = fmaf(kv, vv, acc);
    kss += kv;
  }
  ctxp[tc * 8192 + bh * 256 + p] = acc;
  if (e == 0) ksump[tc * 512 + bh * HD + d] = kss;
}

// ------- Kernel C: attn out + wo + turbo_quant + swiglu + residual + rmsnorm -------
// 512 threads: o = tid&127, ks = tid>>7
__global__ __launch_bounds__(512) void k_attn(
    const float* __restrict__ x, const float* __restrict__ qp,
    const float* __restrict__ ctxp, const float* __restrict__ ksump,
    const float* __restrict__ wo, const float* __restrict__ bo,
    const float* __restrict__ rot, const float* __restrict__ tqs,
    const float* __restrict__ w1, const float* __restrict__ b1,
    const float* __restrict__ w2, const float* __restrict__ b2,
    const float* __restrict__ g2,
    float* __restrict__ xmid, float* __restrict__ h2o) {
  const int tid = threadIdx.x;
  const int o = tid & 127, ks = tid >> 7;
  const int n0 = blockIdx.x * 4;
  const int b = n0 >> 9;
  __shared__ float ctxs[NH * 256];  // 8KB
  __shared__ float kss[DM];
  __shared__ float rowA[4][DM], rowB[4][DM];
  __shared__ float red2[4][4][DM][2];  // 16KB
  __shared__ float wredA[8], wredB[8];

  for (int idx = tid; idx < 2048; idx += 512) {
    float s = 0.0f;
#pragma unroll
    for (int tc = 0; tc < 8; ++tc) s += ctxp[tc * 8192 + b * 2048 + idx];
    ctxs[idx] = s;
  }
  if (tid < 128) {
    float s = 0.0f;
#pragma unroll
    for (int tc = 0; tc < 8; ++tc) s += ksump[tc * 512 + b * DM + tid];
    kss[tid] = s;
  }
  rowA[ks][o] = qp[(n0 + ks) * DM + o];
  __syncthreads();

  // attention: out = q @ ctx, z = 1/(q . ksum)
  {
    int h = o >> 4, e = o & 15;
    float oa = 0.0f, qk = 0.0f;
#pragma unroll
    for (int d = 0; d < HD; ++d) {
      float qv = rowA[ks][h * HD + d];
      oa = fmaf(qv, ctxs[h * 256 + d * 16 + e], oa);
      qk = fmaf(qv, kss[h * HD + d], qk);
    }
    rowB[ks][o] = oa / (qk + 1e-6f);
  }
  __syncthreads();

  const int d0 = ks * 32;
  // @ wo + bo  (k-split partial)
  {
    float acc[4] = {0, 0, 0, 0};
    for (int dd = 0; dd < 32; ++dd) {
      int d = d0 + dd;
      float w = wo[d * DM + o];
#pragma unroll
      for (int g = 0; g < 4; ++g) acc[g] = fmaf(rowB[g][d], w, acc[g]);
    }
#pragma unroll
    for (int g = 0; g < 4; ++g) red2[ks][g][o][0] = acc[g];
  }
  __syncthreads();
  {
    float sa = bo[o];
#pragma unroll
    for (int s2 = 0; s2 < 4; ++s2) sa += red2[s2][ks][o][0];
    rowA[ks][o] = sa;
  }
  __syncthreads();

  // turbo_quant: y = attn_out @ rot
  {
    float acc[4] = {0, 0, 0, 0};
    for (int dd = 0; dd < 32; ++dd) {
      int d = d0 + dd;
      float r = rot[d * DM + o];
#pragma unroll
      for (int g = 0; g < 4; ++g) acc[g] = fmaf(rowA[g][d], r, acc[g]);
    }
#pragma unroll
    for (int g = 0; g < 4; ++g) red2[ks][g][o][1] = acc[g];
  }
  __syncthreads();
  {
    float y = 0.0f;
#pragma unroll
    for (int s2 = 0; s2 < 4; ++s2) y += red2[s2][ks][o][1];
    float ssq = wave_sum64(y * y);
    if ((tid & 63) == 0) wredA[tid >> 6] = ssq;
    __syncthreads();
    float tot = wredA[2 * ks] + wredA[2 * ks + 1];
    float mag = sqrtf(tot * (1.0f / 128.0f) + 1e-6f);
    float phase = y / mag;
    rowB[ks][o] = rintf(phase * 8.0f) * 0.125f * mag * tqs[o];
  }
  __syncthreads();

  // swiglu (w1, w2 k-split)
  {
    float a1[4] = {0, 0, 0, 0}, a2[4] = {0, 0, 0, 0};
    for (int dd = 0; dd < 32; ++dd) {
      int d = d0 + dd;
      float w1v = w1[d * DM + o];
      float w2v = w2[d * DM + o];
#pragma unroll
      for (int g = 0; g < 4; ++g) {
        float t = rowB[g][d];
        a1[g] = fmaf(t, w1v, a1[g]);
        a2[g] = fmaf(t, w2v, a2[g]);
      }
    }
#pragma unroll
    for (int g = 0; g < 4; ++g) {
      red2[ks][g][o][0] = a1[g];
      red2[ks][g][o][1] = a2[g];
    }
  }
  __syncthreads();
  {
    float ga = b1[o], up = b2[o];
#pragma unroll
    for (int s2 = 0; s2 < 4; ++s2) {
      ga += red2[s2][ks][o][0];
      up += red2[s2][ks][o][1];
    }
    float swv = ga * sigmoid_f(ga) * up;
    float xm = x[(n0 + ks) * DM + o] + swv;
    xmid[(n0 + ks) * DM + o] = xm;
    float ssq = wave_sum64(xm * xm);
    if ((tid & 63) == 0) wredB[tid >> 6] = ssq;
    __syncthreads();
    float tot = wredB[2 * ks] + wredB[2 * ks + 1];
    float rinv = 1.0f / sqrtf(tot * (1.0f / 128.0f) + 1e-6f);
    h2o[(n0 + ks) * DM + o] = g2[o] * xm * rinv;
  }
}

// ---------------- Kernel D: MoE ----------------
// 1024 threads, 4 tokens/block, 512 blocks
__global__ __launch_bounds__(1024) void k_moe(
    const float* __restrict__ h2, const float* __restrict__ xmid,
    const float* __restrict__ gate_w, const float* __restrict__ gate_b,
    const float* __restrict__ exp_w,
    const float* __restrict__ mw1, const float* __restrict__ mb1,
    const float* __restrict__ mw2, const float* __restrict__ mb2,
    float* __restrict__ out_x, float* __restrict__ out_cons) {
  const int tid = threadIdx.x;
  const int n0 = blockIdx.x * 4;
  __shared__ float h2s[4][DM];         // 2KB
  __shared__ float redg[4][4][NE];     // 16KB  [kslice][token][e]
  __shared__ float lgl[4][NE];         // 4KB
  __shared__ float el[4][2][DM];       // 4KB
  __shared__ float was[4][DM];         // 2KB
  __shared__ float redm[2][4][DM][2];  // 8KB
  __shared__ int sie[4][2];
  __shared__ float sw[4][2];
  __shared__ float wredV[8];

  if (tid < 512) {
    int g = tid >> 7, o = tid & 127;
    h2s[g][o] = h2[(n0 + g) * DM + o];
  }
  __syncthreads();

  // gate logits: e = tid&255, k-slice kq = tid>>8
  {
    int e = tid & 255, kq = tid >> 8;
    float lg[4] = {0, 0, 0, 0};
    for (int dd = 0; dd < 32; ++dd) {
      int d = kq * 32 + dd;
      float gw = gate_w[d * NE + e];
#pragma unroll
      for (int g = 0; g < 4; ++g) lg[g] = fmaf(h2s[g][d], gw, lg[g]);
    }
#pragma unroll
    for (int g = 0; g < 4; ++g) redg[kq][g][e] = lg[g];
  }
  __syncthreads();
  {
    int e = tid & 255, kq = tid >> 8;  // finalize token kq's logit for expert e
    float lf = gate_b[e];
#pragma unroll
    for (int s2 = 0; s2 < 4; ++s2) lf += redg[s2][kq][e];
    lgl[kq][e] = lf;
  }
  __syncthreads();

  // top-2 softmax: wave w (0..3) handles token w; 256 entries = 4/lane
  if (tid < 256) {
    int lane = tid & 63, g = tid >> 6;
    float bv = -INFINITY;
    int bi = 0;
#pragma unroll
    for (int j2 = 0; j2 < 4; ++j2) {
      int e = lane + 64 * j2;
      float vv = lgl[g][e];
      if (vv > bv || (vv == bv && e < bi)) { bv = vv; bi = e; }
    }
#pragma unroll
    for (int m = 32; m; m >>= 1) {
      float pv = __shfl_xor(bv, m, 64);
      int pi = __shfl_xor(bi, m, 64);
      if (pv > bv || (pv == bv && pi < bi)) { bv = pv; bi = pi; }
    }
    float se = 0.0f;
#pragma unroll
    for (int j2 = 0; j2 < 4; ++j2) se += expf(lgl[g][lane + 64 * j2] - bv);
    se = wave_sum64(se);
    float mv = -INFINITY;
    int mi = 0;
#pragma unroll
    for (int j2 = 0; j2 < 4; ++j2) {
      int e = lane + 64 * j2;
      if (e != bi) {
        float vv = lgl[g][e];
        if (vv > mv || (vv == mv && e < mi)) { mv = vv; mi = e; }
      }
    }
#pragma unroll
    for (int m = 32; m; m >>= 1) {
      float pv = __shfl_xor(mv, m, 64);
      int pi = __shfl_xor(mi, m, 64);
      if (pv > mv || (pv == mv && pi < mi)) { mv = pv; mi = pi; }
    }
    if (lane == 0) {
      float v0 = 1.0f / se;
      float v1 = expf(mv - bv) / se;
      float wsum = v0 + v1 + 1e-6f;
      sie[g][0] = bi;
      sie[g][1] = mi;
      sw[g][0] = v0 / wsum;
      sw[g][1] = v1 / wsum;
    }
  }
  __syncthreads();

  // expert matmuls: 8 assignments (token x slot) x 128 outputs
  {
    int asn = tid >> 7, o = tid & 127;
    int g = asn >> 1, slot = asn & 1;
    const float* W = exp_w + (size_t)sie[g][slot] * (DM * DM);
    float ea = 0.0f;
    for (int d = 0; d < DM; ++d) ea = fmaf(h2s[g][d], W[d * DM + o], ea);
    el[g][slot][o] = ea;
  }
  __syncthreads();
  if (tid < 512) {
    int g = tid >> 7, o = tid & 127;
    was[g][o] = sw[g][0] * el[g][0][o] + sw[g][1] * el[g][1][o];
  }
  __syncthreads();

  // moe swiglu (2-way k-split)
  {
    int kh = tid >> 9, r = tid & 511, g = r >> 7, o = r & 127;
    float a1 = 0.0f, a2 = 0.0f;
    for (int dd = 0; dd < 64; ++dd) {
      int d = kh * 64 + dd;
      float w1v = mw1[d * DM + o];
      float w2v = mw2[d * DM + o];
      float t = was[g][d];
      a1 = fmaf(t, w1v, a1);
      a2 = fmaf(t, w2v, a2);
    }
    redm[kh][g][o][0] = a1;
    redm[kh][g][o][1] = a2;
  }
  __syncthreads();
  if (tid < 512) {
    int g = tid >> 7, o = tid & 127;
    float ga = redm[0][g][o][0] + redm[1][g][o][0] + mb1[o];
    float up = redm[0][g][o][1] + redm[1][g][o][1] + mb2[o];
    float swv = ga * sigmoid_f(ga) * up;
    out_x[(size_t)(n0 + g) * DM + o] = xmid[(size_t)(n0 + g) * DM + o] + swv;
    float dd0 = el[g][0][o] - swv;
    float dd1 = el[g][1][o] - swv;
    float vt = sw[g][0] * dd0 * dd0 + sw[g][1] * dd1 * dd1;
    vt = wave_sum64(vt);
    if ((tid & 63) == 0) wredV[tid >> 6] = vt;
  }
  __syncthreads();
  if (tid < 4)
    out_cons[n0 + tid] = expf(-(wredV[2 * tid] + wredV[2 * tid + 1]) * (1.0f / 128.0f));
}

extern "C" void kernel_launch(void* const* d_in, const int* in_sizes, int n_in,
                              void* d_out, int out_size, void* d_ws, size_t ws_size,
                              hipStream_t stream) {
  const float* x = (const float*)d_in[0];
  const float* g1 = (const float*)d_in[1];
  const float* wq = (const float*)d_in[2];
  const float* bq = (const float*)d_in[3];
  const float* wk = (const float*)d_in[4];
  const float* bk = (const float*)d_in[5];
  const float* wv = (const float*)d_in[6];
  const float* bv = (const float*)d_in[7];
  const float* wo = (const float*)d_in[8];
  const float* bo = (const float*)d_in[9];
  const float* rot = (const float*)d_in[10];
  const float* tqs = (const float*)d_in[11];
  const float* sw1 = (const float*)d_in[12];
  const float* sb1 = (const float*)d_in[13];
  const float* sw2 = (const float*)d_in[14];
  const float* sb2 = (const float*)d_in[15];
  const float* g2 = (const float*)d_in[16];
  const float* gw = (const float*)d_in[17];
  const float* gb = (const float*)d_in[18];
  const float* ew = (const float*)d_in[19];
  const float* mw1 = (const float*)d_in[20];
  const float* mb1 = (const float*)d_in[21];
  const float* mw2 = (const float*)d_in[22];
  const float* mb2 = (const float*)d_in[23];

  float* ws = (float*)d_ws;
  float* q = ws;                 // 262144
  float* k = ws + 262144;        // 262144
  float* v = ws + 524288;        // 262144
  float* ctxp = ws + 786432;     // 8*32*256 = 65536
  float* ksump = ws + 851968;    // 8*512 = 4096
  float* xmid = ws + 856064;     // 262144
  float* h2 = ws + 1118208;      // 262144
  float* out_x = (float*)d_out;
  float* out_c = out_x + (size_t)NTOK * DM;

  hipLaunchKernelGGL(k_qkv, dim3(NTOK / 4), dim3(512), 0, stream,
                     x, g1, wq, bq, wk, bk, wv, bv, q, k, v);
  hipLaunchKernelGGL(k_ctxp, dim3(256), dim3(256), 0, stream, k, v, ctxp, ksump);
  hipLaunchKernelGGL(k_attn, dim3(NTOK / 4), dim3(512), 0, stream,
                     x, q, ctxp, ksump, wo, bo, rot, tqs, sw1, sb1, sw2, sb2, g2,
                     xmid, h2);
  hipLaunchKernelGGL(k_moe, dim3(NTOK / 4), dim3(1024), 0, stream,
                     h2, xmid, gw, gb, ew, mw1, mb1, mw2, mb2, out_x, out_c);
}